// Round 18
// baseline (2855.658 us; speedup 1.0000x reference)
//
#include <hip/hip_runtime.h>

typedef __bf16 bf16;
typedef __bf16 bf16x4 __attribute__((ext_vector_type(4)));
typedef __bf16 bf16x8 __attribute__((ext_vector_type(8)));
typedef float  f32x4  __attribute__((ext_vector_type(4)));
typedef unsigned int u32;

#define GLD_LDS16(gsrc, ldst) \
  __builtin_amdgcn_global_load_lds((const __attribute__((address_space(1))) u32*)(gsrc), \
                                   (__attribute__((address_space(3))) u32*)(ldst), 16, 0, 0)

static __device__ __forceinline__ float sigmoidf_(float x) { return 1.0f / (1.0f + expf(-x)); }

__global__ void fill_guard(float* __restrict__ utt, float v) {
  int i = blockIdx.x * 256 + threadIdx.x;
  if (i < 131072) utt[i] = v;
}

// ---------------- H = bf16(x + pos_emb) ----------------
__global__ void add_pos_bf(const float* __restrict__ x, const float* __restrict__ pos,
                           bf16* __restrict__ H) {
  size_t i = ((size_t)blockIdx.x * 256 + threadIdx.x) * 4;
  if (i >= 32768000ull) return;
  int d = (int)(i & 1023);
  int s = (int)((i >> 10) % 500);
  float4 xv = *(const float4*)(x + i);
  float4 pv = *(const float4*)(pos + (size_t)s * 1024 + d);
  bf16x4 o;
  o[0] = (bf16)(xv.x + pv.x); o[1] = (bf16)(xv.y + pv.y);
  o[2] = (bf16)(xv.z + pv.z); o[3] = (bf16)(xv.w + pv.w);
  *(bf16x4*)(H + i) = o;
}

// ---------------- weight transpose+convert: fp32 [R][C] -> bf16 [C][R] ----------------
__global__ void wtrans(const float* __restrict__ src, bf16* __restrict__ dst, int R, int C) {
  __shared__ float tile[32][33];
  int c0 = blockIdx.x * 32, r0 = blockIdx.y * 32;
  int tr = threadIdx.x >> 5, tc = threadIdx.x & 31;
#pragma unroll
  for (int i = 0; i < 4; ++i)
    tile[tr + i * 8][tc] = src[(size_t)(r0 + tr + i * 8) * C + c0 + tc];
  __syncthreads();
#pragma unroll
  for (int i = 0; i < 4; ++i) {
    int rr = tr + i * 8;
    dst[(size_t)(c0 + rr) * R + r0 + tc] = (bf16)tile[tc][rr];
  }
}

// ================= 256x256 BK=64 8-wave GEMM, swizzled LDS, counted vmcnt =================
// C[m,n] = scale*sum_k A[m,k]*Bt[n,k] (+bias) + epilogue (EPI as in mgemm).
// LDS: dynamic 128KB = 2 bufs x (A 32KB + B 32KB). Swizzle: byte ^= (row&7)<<4 (16B chunks),
// realized as pre-swizzled GLOBAL source (linear global_load_lds dest) + swizzled ds_read.
template <int EPI, typename TC>
__global__ __launch_bounds__(512, 2) void mgemm256(
    const bf16* __restrict__ A, const bf16* __restrict__ A2, int ksplit,
    const bf16* __restrict__ Bt, const float* __restrict__ bias, TC* __restrict__ C,
    bf16* __restrict__ Cbf,
    int M, int N, int K, int lda, int ldb, int ldc, int c_off, float scale,
    const bf16* __restrict__ Gh, const bf16* __restrict__ Gm) {
  extern __shared__ char sm[];  // buf c: A @ c*65536, B @ c*65536+32768
  const int t = threadIdx.x;

  // T1: bijective XCD-aware block remap (m204)
  const int gx = gridDim.x;
  const int nwg = gx * gridDim.y;
  const int orig = blockIdx.y * gx + blockIdx.x;
  const int qq = nwg >> 3, r8 = nwg & 7;
  const int xcd = orig & 7, lo = orig >> 3;
  const int wg = (xcd < r8 ? xcd * (qq + 1) : r8 * (qq + 1) + (xcd - r8) * qq) + lo;
  const int m0 = (wg / gx) * 256, n0 = (wg % gx) * 256;

  const int lane = t & 63;
  const int w = t >> 6, wr = w >> 2, wc = w & 3;  // 2x4 waves, each owns 128x64
  const int srow = t >> 3, schunk = t & 7, scol = schunk * 8;  // staging
  const int hi16 = (lane >> 4) << 4;  // frag k-byte base

  f32x4 acc[8][4];
#pragma unroll
  for (int i = 0; i < 8; ++i)
#pragma unroll
    for (int j = 0; j < 4; ++j)
#pragma unroll
      for (int c = 0; c < 4; ++c) acc[i][j][c] = 0.0f;

  // stage quarter h of K-tile tt into buffer cb: h 0,1 = A halves; 2,3 = B halves.
#define STAGE_Q(tt, cb, h) do {                                                     \
    const int k0s_ = (tt) * 64;                                                     \
    char* lb_ = sm + (cb) * 65536 + ((h) < 2 ? 0 : 32768);                          \
    _Pragma("unroll")                                                               \
    for (int i_ = 0; i_ < 2; ++i_) {                                                \
      int rl_ = ((h) & 1) * 128 + i_ * 64 + srow;                                   \
      int cx_ = scol ^ ((rl_ & 7) << 3);                                            \
      if ((h) < 2) {                                                                \
        int rg_ = m0 + rl_; rg_ = rg_ < M ? rg_ : M - 1;                            \
        const bf16* s_ = (k0s_ < ksplit)                                            \
            ? A  + (size_t)rg_ * lda + k0s_ + cx_                                   \
            : A2 + (size_t)rg_ * lda + (k0s_ - ksplit) + cx_;                       \
        GLD_LDS16(s_, lb_ + rl_ * 128 + schunk * 16);                               \
      } else {                                                                      \
        int rg_ = n0 + rl_; rg_ = rg_ < N ? rg_ : N - 1;                            \
        GLD_LDS16(Bt + (size_t)rg_ * ldb + k0s_ + cx_, lb_ + rl_ * 128 + schunk * 16); \
      }                                                                             \
    }                                                                               \
  } while (0)

  const int NT = K >> 6;
  // prologue: tile 0 -> buf 0 (8 gloads)
  STAGE_Q(0, 0, 0); STAGE_Q(0, 0, 1); STAGE_Q(0, 0, 2); STAGE_Q(0, 0, 3);

  for (int t0 = 0; t0 < NT; ++t0) {
    const int cur = t0 & 1;
    char* smA = sm + cur * 65536;
    char* smB = smA + 32768;
    const bool pf = (t0 + 1 < NT);

    // ---- phase 0: prefetch q0, counted wait for tile t0, read B frags + A rows 0-1 ----
    if (pf) {
      STAGE_Q(t0 + 1, cur ^ 1, 0);
      asm volatile("s_waitcnt vmcnt(2)" ::: "memory");
    } else {
      asm volatile("s_waitcnt vmcnt(0)" ::: "memory");
    }
    __builtin_amdgcn_s_barrier();

    bf16x8 bfr[4][2];
#pragma unroll
    for (int fc = 0; fc < 4; ++fc)
#pragma unroll
      for (int ks = 0; ks < 2; ++ks) {
        int rb = wc * 64 + fc * 16 + (lane & 15);
        int byb = (ks * 64 + hi16) ^ ((rb & 7) << 4);
        bfr[fc][ks] = *(const bf16x8*)(smB + rb * 128 + byb);
      }

#pragma unroll
    for (int p = 0; p < 4; ++p) {
      if (p > 0 && pf) STAGE_Q(t0 + 1, cur ^ 1, p);
      bf16x8 afr[2][2];
#pragma unroll
      for (int e = 0; e < 2; ++e)
#pragma unroll
        for (int ks = 0; ks < 2; ++ks) {
          int ra = wr * 128 + (2 * p + e) * 16 + (lane & 15);
          int bya = (ks * 64 + hi16) ^ ((ra & 7) << 4);
          afr[e][ks] = *(const bf16x8*)(smA + ra * 128 + bya);
        }
      if (p > 0) __builtin_amdgcn_s_barrier();
      __builtin_amdgcn_s_setprio(1);
#pragma unroll
      for (int e = 0; e < 2; ++e)
#pragma unroll
        for (int fc = 0; fc < 4; ++fc)
#pragma unroll
          for (int ks = 0; ks < 2; ++ks)
            acc[2 * p + e][fc] = __builtin_amdgcn_mfma_f32_16x16x32_bf16(
                afr[e][ks], bfr[fc][ks], acc[2 * p + e][fc], 0, 0, 0);
      __builtin_amdgcn_s_setprio(0);
      __builtin_amdgcn_s_barrier();
    }
  }
#undef STAGE_Q

  // epilogue
#pragma unroll
  for (int fr = 0; fr < 8; ++fr) {
#pragma unroll
    for (int j4 = 0; j4 < 4; ++j4) {
      int m = m0 + wr * 128 + fr * 16 + ((lane >> 4) << 2) + j4;
      if (m >= M) continue;
#pragma unroll
      for (int fc = 0; fc < 4; ++fc) {
        int n = n0 + wc * 64 + fc * 16 + (lane & 15);
        if (n >= N) continue;
        float v = acc[fr][fc][j4] * scale;
        if (bias) v += bias[n];
        if (EPI == 1) v = sigmoidf_(v);
        if (EPI == 2) {
          float g = sigmoidf_(v);
          float h  = (float)Gh[(size_t)m * 1024 + n];
          float hm = (float)Gm[(size_t)m * 1024 + n];
          v = g * h + (1.0f - g) * hm;
        }
        if (EPI == 3) {
          unsigned b = (unsigned)m / 500u;
          unsigned s = (unsigned)m - b * 500u;
          C[(size_t)b * 524288 + (size_t)n * 512 + s] = (TC)v;
        } else {
          C[(size_t)m * ldc + c_off + n] = (TC)v;
          if (EPI == 2 && Cbf) Cbf[(size_t)m * 2048 + c_off + n] = (bf16)v;
        }
      }
    }
  }
}

// ---------------- 128x128 MFMA GEMM (kept for batched QK^T / PV) ----------------
template <int EPI, typename TC>
__global__ __launch_bounds__(256, 2) void mgemm(
    const bf16* __restrict__ A, const bf16* __restrict__ A2, int ksplit,
    const bf16* __restrict__ Bt, const float* __restrict__ bias, TC* __restrict__ C,
    int M, int N, int K, int lda, int ldb, int ldc, int c_off, float scale,
    long long sA, long long sB, long long sC,
    const bf16* __restrict__ Gh, const bf16* __restrict__ Gm) {
  __shared__ __align__(16) char sm[16384];
  const int t = threadIdx.x;
  const long long bz = blockIdx.z;
  A += bz * sA; A2 += bz * sA; Bt += bz * sB; C += bz * sC;
  const int m0 = blockIdx.y * 128, n0 = blockIdx.x * 128;

  f32x4 acc[4][4];
#pragma unroll
  for (int i = 0; i < 4; ++i)
#pragma unroll
    for (int j = 0; j < 4; ++j)
#pragma unroll
      for (int c = 0; c < 4; ++c) acc[i][j][c] = 0.0f;

  const int lane = t & 63;
  const int wv = t >> 6, wm = (wv >> 1) * 64, wn = (wv & 1) * 64;
  const int lr = lane & 15, lkb = (lane >> 4) * 16;
  const int rr = t >> 2, cc = (t & 3) * 8;

  for (int k0 = 0; k0 < K; k0 += 32) {
    const bf16* Ak = (k0 < ksplit) ? (A + k0) : (A2 + (k0 - ksplit));
    const bf16* Bk = Bt + k0;
#pragma unroll
    for (int j = 0; j < 2; ++j) {
      int ra = m0 + j * 64 + rr; ra = ra < M ? ra : M - 1;
      GLD_LDS16(Ak + (size_t)ra * lda + cc, sm + j * 4096 + t * 16);
      int rb = n0 + j * 64 + rr; rb = rb < N ? rb : N - 1;
      GLD_LDS16(Bk + (size_t)rb * ldb + cc, sm + 8192 + j * 4096 + t * 16);
    }
    asm volatile("s_waitcnt vmcnt(0)" ::: "memory");
    __syncthreads();

    bf16x8 av[4], bv[4];
#pragma unroll
    for (int i = 0; i < 4; ++i) {
      av[i] = *(const bf16x8*)(sm + (wm + i * 16 + lr) * 64 + lkb);
      bv[i] = *(const bf16x8*)(sm + 8192 + (wn + i * 16 + lr) * 64 + lkb);
    }
#pragma unroll
    for (int i = 0; i < 4; ++i)
#pragma unroll
      for (int j = 0; j < 4; ++j)
        acc[i][j] = __builtin_amdgcn_mfma_f32_16x16x32_bf16(av[i], bv[j], acc[i][j], 0, 0, 0);
    __syncthreads();
  }

#pragma unroll
  for (int i = 0; i < 4; ++i) {
#pragma unroll
    for (int j4 = 0; j4 < 4; ++j4) {
      int m = m0 + wm + i * 16 + (lane >> 4) * 4 + j4;
      if (m >= M) continue;
#pragma unroll
      for (int j = 0; j < 4; ++j) {
        int n = n0 + wn + j * 16 + (lane & 15);
        if (n >= N) continue;
        float v = acc[i][j][j4] * scale;
        if (bias) v += bias[n];
        C[(size_t)m * ldc + c_off + n] = (TC)v;
      }
    }
  }
}

// ---------------- masked softmax, wave-parallel ----------------
__global__ void attn_softmax_w(const float* __restrict__ S, bf16* __restrict__ P, int fw) {
  int row = blockIdx.x * 4 + (threadIdx.x >> 6);
  int lane = threadIdx.x & 63;
  int q = row % 500;
  const float* Srow = S + (size_t)row * 512;
  bf16* Prow = P + (size_t)row * 512;
  int klo = fw ? 0 : q;
  int khi = fw ? q : 499;

  float xv[8];
  float m = -1e30f;
#pragma unroll
  for (int i = 0; i < 8; ++i) {
    int k = lane + i * 64;
    bool valid = (k >= klo) & (k <= khi);
    float v = valid ? Srow[k] : -1e30f;
    xv[i] = v;
    m = fmaxf(m, v);
  }
#pragma unroll
  for (int off = 32; off > 0; off >>= 1) m = fmaxf(m, __shfl_xor(m, off, 64));
  float e[8];
  float sum = 0.0f;
#pragma unroll
  for (int i = 0; i < 8; ++i) {
    e[i] = (xv[i] > -1e29f) ? expf(xv[i] - m) : 0.0f;
    sum += e[i];
  }
#pragma unroll
  for (int off = 32; off > 0; off >>= 1) sum += __shfl_xor(sum, off, 64);
  float inv = 1.0f / sum;
#pragma unroll
  for (int i = 0; i < 8; ++i) Prow[lane + i * 64] = (bf16)(e[i] * inv);
}

// ---------------- final: online softmax over seq + weighted sum ----------------
__global__ void final_reduce_chunk(const float* __restrict__ s2, const float* __restrict__ Ci,
                                   float* __restrict__ utt) {
  int c = blockIdx.x * 256 + threadIdx.x;
  int b = blockIdx.y;
  if (c >= 2048) return;
  float m = -1e30f, sum = 0.0f, acc = 0.0f;
  for (int s = 0; s < 500; ++s) {
    size_t idx = ((size_t)(b * 500 + s)) * 2048 + c;
    float xx = s2[idx];
    float ci = Ci[idx];
    float mn = fmaxf(m, xx);
    float corr = expf(m - mn);
    float e = expf(xx - mn);
    sum = sum * corr + e;
    acc = acc * corr + e * ci;
    m = mn;
  }
  utt[(size_t)b * 2048 + c] = acc / sum;
}

// ---------------- launcher ----------------
extern "C" void kernel_launch(void* const* d_in, const int* in_sizes, int n_in,
                              void* d_out, int out_size, void* d_ws, size_t ws_size,
                              hipStream_t stream) {
  (void)in_sizes; (void)n_in; (void)out_size;
  float* utt = (float*)d_out;
  float* Ci  = (float*)d_out + 131072;

  const float* x     = (const float*)d_in[0];
  const float* pos   = (const float*)d_in[1];
  const float* Wq_fw = (const float*)d_in[2];  const float* bq_fw = (const float*)d_in[3];
  const float* Wk_fw = (const float*)d_in[4];  const float* bk_fw = (const float*)d_in[5];
  const float* Wv_fw = (const float*)d_in[6];  const float* bv_fw = (const float*)d_in[7];
  const float* Wq_bw = (const float*)d_in[8];  const float* bq_bw = (const float*)d_in[9];
  const float* Wk_bw = (const float*)d_in[10]; const float* bk_bw = (const float*)d_in[11];
  const float* Wv_bw = (const float*)d_in[12]; const float* bv_bw = (const float*)d_in[13];
  const float* Wg_fw = (const float*)d_in[14]; const float* bg_fw = (const float*)d_in[15];
  const float* Wg_bw = (const float*)d_in[16]; const float* bg_bw = (const float*)d_in[17];
  const float* W2    = (const float*)d_in[18]; const float* b2    = (const float*)d_in[19];
  const float* W1    = (const float*)d_in[20]; const float* b1    = (const float*)d_in[21];

  const size_t WS_BYTES = 465305600ull;
  if (ws_size < WS_BYTES) { fill_guard<<<512, 256, 0, stream>>>(utt, 500.0f); return; }

  char* wsb = (char*)d_ws;
  bf16*  Hbf  = (bf16*)(wsb);
  bf16*  Qb   = (bf16*)(wsb + 65536000);
  bf16*  Kb   = (bf16*)(wsb + 131072000);
  bf16*  Vt   = (bf16*)(wsb + 196608000);
  float* Sb   = (float*)(wsb + 263716864);
  bf16*  Hmb  = (bf16*)(wsb + 263716864);
  bf16*  Pb   = (bf16*)(wsb + 329252864);
  char*  wts  = wsb + 362020864;
  bf16* WqF = (bf16*)(wts);             bf16* WkF = (bf16*)(wts + 2097152);
  bf16* WvF = (bf16*)(wts + 4194304);   bf16* WqB = (bf16*)(wts + 6291456);
  bf16* WkB = (bf16*)(wts + 8388608);   bf16* WvB = (bf16*)(wts + 10485760);
  bf16* WgF = (bf16*)(wts + 12582912);  bf16* WgB = (bf16*)(wts + 16777216);
  bf16* W2t = (bf16*)(wts + 20971520);  bf16* W1t = (bf16*)(wts + 29360128);
  bf16*  Cibf  = (bf16*)(wsb + 399769600);
  bf16*  activ = (bf16*)(wsb + 131072000);
  float* s2b   = (float*)(wsb);

  // allow 128KB dynamic LDS for the 256^2 kernel instantiations
  hipFuncSetAttribute(reinterpret_cast<const void*>(&mgemm256<0, bf16>),
                      hipFuncAttributeMaxDynamicSharedMemorySize, 131072);
  hipFuncSetAttribute(reinterpret_cast<const void*>(&mgemm256<3, bf16>),
                      hipFuncAttributeMaxDynamicSharedMemorySize, 131072);
  hipFuncSetAttribute(reinterpret_cast<const void*>(&mgemm256<2, float>),
                      hipFuncAttributeMaxDynamicSharedMemorySize, 131072);
  hipFuncSetAttribute(reinterpret_cast<const void*>(&mgemm256<1, bf16>),
                      hipFuncAttributeMaxDynamicSharedMemorySize, 131072);
  hipFuncSetAttribute(reinterpret_cast<const void*>(&mgemm256<0, float>),
                      hipFuncAttributeMaxDynamicSharedMemorySize, 131072);

  add_pos_bf<<<32000, 256, 0, stream>>>(x, pos, Hbf);

  struct WT { const float* s; bf16* d; int R, C; } wt[10] = {
      {Wq_fw, WqF, 1024, 1024}, {Wk_fw, WkF, 1024, 1024}, {Wv_fw, WvF, 1024, 1024},
      {Wq_bw, WqB, 1024, 1024}, {Wk_bw, WkB, 1024, 1024}, {Wv_bw, WvB, 1024, 1024},
      {Wg_fw, WgF, 2048, 1024}, {Wg_bw, WgB, 2048, 1024},
      {W2,    W2t, 2048, 2048}, {W1,    W1t, 2048, 2048}};
  for (int i = 0; i < 10; ++i)
    wtrans<<<dim3(wt[i].C / 32, wt[i].R / 32), 256, 0, stream>>>(wt[i].s, wt[i].d, wt[i].R, wt[i].C);

  const int BIG = 1 << 30;
  for (int dir = 0; dir < 2; ++dir) {
    const bf16* WqT = dir ? WqB : WqF;  const float* bq = dir ? bq_bw : bq_fw;
    const bf16* WkT = dir ? WkB : WkF;  const float* bk = dir ? bk_bw : bk_fw;
    const bf16* WvT = dir ? WvB : WvF;  const float* bv = dir ? bv_bw : bv_fw;
    const bf16* WgT = dir ? WgB : WgF;  const float* bg = dir ? bg_bw : bg_fw;

    // Q/K = H @ W + b   [32000,1024] (256^2 kernel)
    mgemm256<0, bf16><<<dim3(4, 125), 512, 131072, stream>>>(
        Hbf, Hbf, BIG, WqT, bq, Qb, nullptr, 32000, 1024, 1024, 1024, 1024, 1024, 0, 1.0f,
        nullptr, nullptr);
    mgemm256<0, bf16><<<dim3(4, 125), 512, 131072, stream>>>(
        Hbf, Hbf, BIG, WkT, bk, Kb, nullptr, 32000, 1024, 1024, 1024, 1024, 1024, 0, 1.0f,
        nullptr, nullptr);
    // V -> Vt[b][d][s]
    mgemm256<3, bf16><<<dim3(4, 125), 512, 131072, stream>>>(
        Hbf, Hbf, BIG, WvT, bv, Vt, nullptr, 32000, 1024, 1024, 1024, 1024, 512, 0, 1.0f,
        nullptr, nullptr);
    // S = Q K^T / 32  (batched, 128^2 kernel)
    mgemm<0, float><<<dim3(4, 4, 64), 256, 0, stream>>>(
        Qb, Qb, BIG, Kb, nullptr, Sb, 500, 500, 1024, 1024, 1024, 512, 0, 0.03125f,
        512000, 512000, 256000, nullptr, nullptr);
    attn_softmax_w<<<8000, 256, 0, stream>>>(Sb, Pb, dir == 0 ? 1 : 0);
    // Hm = P @ V (batched)
    mgemm<0, bf16><<<dim3(8, 4, 64), 256, 0, stream>>>(
        Pb, Pb, BIG, Vt, nullptr, Hmb, 500, 1024, 512, 512, 512, 1024, 0, 1.0f,
        256000, 524288, 512000, nullptr, nullptr);
    // gate -> f32 Ci + bf16 Cibf (256^2, split A)
    mgemm256<2, float><<<dim3(8, 125), 512, 131072, stream>>>(
        Hbf, Hmb, 1024, WgT, bg, Ci, Cibf, 32000, 1024, 2048, 1024, 2048, 2048,
        dir == 0 ? 0 : 1024, 1.0f, Hbf, Hmb);
  }

  // activ = sigmoid(Cibf @ W2 + b2)
  mgemm256<1, bf16><<<dim3(8, 125), 512, 131072, stream>>>(
      Cibf, Cibf, BIG, W2t, b2, activ, nullptr, 32000, 2048, 2048, 2048, 2048, 2048, 0, 1.0f,
      nullptr, nullptr);

  // scores2 + online final reduce in 2 chunks of 32 batches
  for (int c0 = 0; c0 < 2; ++c0) {
    mgemm256<0, float><<<dim3(8, 63), 512, 131072, stream>>>(
        activ + (size_t)c0 * 16000 * 2048, activ, BIG, W1t, b1, s2b, nullptr,
        16000, 2048, 2048, 2048, 2048, 2048, 0, 1.0f, nullptr, nullptr);
    final_reduce_chunk<<<dim3(8, 32), 256, 0, stream>>>(
        s2b, Ci + (size_t)c0 * 32 * 500 * 2048, utt + (size_t)c0 * 32 * 2048);
  }
}

// Round 19
// 2827.119 us; speedup vs baseline: 1.0101x; 1.0101x over previous
//
#include <hip/hip_runtime.h>

typedef __bf16 bf16;
typedef __bf16 bf16x4 __attribute__((ext_vector_type(4)));
typedef __bf16 bf16x8 __attribute__((ext_vector_type(8)));
typedef float  f32x4  __attribute__((ext_vector_type(4)));
typedef unsigned int u32;

#define GLD_LDS16(gsrc, ldst) \
  __builtin_amdgcn_global_load_lds((const __attribute__((address_space(1))) u32*)(gsrc), \
                                   (__attribute__((address_space(3))) u32*)(ldst), 16, 0, 0)

static __device__ __forceinline__ float sigmoidf_(float x) { return 1.0f / (1.0f + expf(-x)); }

__global__ void fill_guard(float* __restrict__ utt, float v) {
  int i = blockIdx.x * 256 + threadIdx.x;
  if (i < 131072) utt[i] = v;
}

// ---------------- H = bf16(x + pos_emb) ----------------
__global__ void add_pos_bf(const float* __restrict__ x, const float* __restrict__ pos,
                           bf16* __restrict__ H) {
  size_t i = ((size_t)blockIdx.x * 256 + threadIdx.x) * 4;
  if (i >= 32768000ull) return;
  int d = (int)(i & 1023);
  int s = (int)((i >> 10) % 500);
  float4 xv = *(const float4*)(x + i);
  float4 pv = *(const float4*)(pos + (size_t)s * 1024 + d);
  bf16x4 o;
  o[0] = (bf16)(xv.x + pv.x); o[1] = (bf16)(xv.y + pv.y);
  o[2] = (bf16)(xv.z + pv.z); o[3] = (bf16)(xv.w + pv.w);
  *(bf16x4*)(H + i) = o;
}

// ---------------- weight transpose+convert: fp32 [R][C] -> bf16 [C][R] ----------------
__global__ void wtrans(const float* __restrict__ src, bf16* __restrict__ dst, int R, int C) {
  __shared__ float tile[32][33];
  int c0 = blockIdx.x * 32, r0 = blockIdx.y * 32;
  int tr = threadIdx.x >> 5, tc = threadIdx.x & 31;
#pragma unroll
  for (int i = 0; i < 4; ++i)
    tile[tr + i * 8][tc] = src[(size_t)(r0 + tr + i * 8) * C + c0 + tc];
  __syncthreads();
#pragma unroll
  for (int i = 0; i < 4; ++i) {
    int rr = tr + i * 8;
    dst[(size_t)(c0 + rr) * R + r0 + tc] = (bf16)tile[tc][rr];
  }
}

// ================= 256x256 BK=64 8-wave GEMM, pipelined frags, counted sync =================
// One vmcnt(0)+barrier per K-tile; fragment ds_reads ONE PHASE AHEAD so MFMA hides LDS latency;
// global_load_lds staging of tile t+1 interleaved with tile t compute. Swizzle byte^=(row&7)<<4.
template <int EPI, typename TC>
__global__ __launch_bounds__(512, 2) void mgemm256(
    const bf16* __restrict__ A, const bf16* __restrict__ A2, int ksplit,
    const bf16* __restrict__ Bt, const float* __restrict__ bias, TC* __restrict__ C,
    bf16* __restrict__ Cbf,
    int M, int N, int K, int lda, int ldb, int ldc, int c_off, float scale,
    const bf16* __restrict__ Gh, const bf16* __restrict__ Gm) {
  extern __shared__ char sm[];  // buf c: A @ c*65536, B @ c*65536+32768
  const int t = threadIdx.x;

  // T1: bijective XCD-aware block remap (m204)
  const int gx = gridDim.x;
  const int nwg = gx * gridDim.y;
  const int orig = blockIdx.y * gx + blockIdx.x;
  const int qq = nwg >> 3, r8 = nwg & 7;
  const int xcd = orig & 7, lo = orig >> 3;
  const int wg = (xcd < r8 ? xcd * (qq + 1) : r8 * (qq + 1) + (xcd - r8) * qq) + lo;
  const int m0 = (wg / gx) * 256, n0 = (wg % gx) * 256;

  const int lane = t & 63;
  const int w = t >> 6, wr = w >> 2, wc = w & 3;  // 2x4 waves, each owns 128x64
  const int srow = t >> 3, schunk = t & 7, scol = schunk * 8;
  const int hi16 = (lane >> 4) << 4;

  f32x4 acc[8][4];
#pragma unroll
  for (int i = 0; i < 8; ++i)
#pragma unroll
    for (int j = 0; j < 4; ++j)
#pragma unroll
      for (int c = 0; c < 4; ++c) acc[i][j][c] = 0.0f;

#define STAGE_Q(tt, cb, h) do {                                                     \
    const int k0s_ = (tt) * 64;                                                     \
    char* lb_ = sm + (cb) * 65536 + ((h) < 2 ? 0 : 32768);                          \
    _Pragma("unroll")                                                               \
    for (int i_ = 0; i_ < 2; ++i_) {                                                \
      int rl_ = ((h) & 1) * 128 + i_ * 64 + srow;                                   \
      int cx_ = scol ^ ((rl_ & 7) << 3);                                            \
      if ((h) < 2) {                                                                \
        int rg_ = m0 + rl_; rg_ = rg_ < M ? rg_ : M - 1;                            \
        const bf16* s_ = (k0s_ < ksplit)                                            \
            ? A  + (size_t)rg_ * lda + k0s_ + cx_                                   \
            : A2 + (size_t)rg_ * lda + (k0s_ - ksplit) + cx_;                       \
        GLD_LDS16(s_, lb_ + rl_ * 128 + schunk * 16);                               \
      } else {                                                                      \
        int rg_ = n0 + rl_; rg_ = rg_ < N ? rg_ : N - 1;                            \
        GLD_LDS16(Bt + (size_t)rg_ * ldb + k0s_ + cx_, lb_ + rl_ * 128 + schunk * 16); \
      }                                                                             \
    }                                                                               \
  } while (0)

  const int NT = K >> 6;
  STAGE_Q(0, 0, 0); STAGE_Q(0, 0, 1); STAGE_Q(0, 0, 2); STAGE_Q(0, 0, 3);

  for (int t0 = 0; t0 < NT; ++t0) {
    const int cur = t0 & 1;
    char* smA = sm + cur * 65536;
    char* smB = smA + 32768;
    const bool pf = (t0 + 1 < NT);

    asm volatile("s_waitcnt vmcnt(0)" ::: "memory");
    __builtin_amdgcn_s_barrier();

    // preload all B fragments + phase-0 A fragments
    bf16x8 bfr[4][2];
#pragma unroll
    for (int fc = 0; fc < 4; ++fc)
#pragma unroll
      for (int ks = 0; ks < 2; ++ks) {
        int rb = wc * 64 + fc * 16 + (lane & 15);
        int byb = (ks * 64 + hi16) ^ ((rb & 7) << 4);
        bfr[fc][ks] = *(const bf16x8*)(smB + rb * 128 + byb);
      }
    bf16x8 afr[2][2][2];  // [parity][e][ks]
#pragma unroll
    for (int e = 0; e < 2; ++e)
#pragma unroll
      for (int ks = 0; ks < 2; ++ks) {
        int ra = wr * 128 + e * 16 + (lane & 15);
        int bya = (ks * 64 + hi16) ^ ((ra & 7) << 4);
        afr[0][e][ks] = *(const bf16x8*)(smA + ra * 128 + bya);
      }

#pragma unroll
    for (int p = 0; p < 4; ++p) {
      if (pf) STAGE_Q(t0 + 1, cur ^ 1, p);          // stage quarter of next tile
      if (p < 3) {                                   // read NEXT phase's A frags
#pragma unroll
        for (int e = 0; e < 2; ++e)
#pragma unroll
          for (int ks = 0; ks < 2; ++ks) {
            int ra = wr * 128 + (2 * (p + 1) + e) * 16 + (lane & 15);
            int bya = (ks * 64 + hi16) ^ ((ra & 7) << 4);
            afr[(p + 1) & 1][e][ks] = *(const bf16x8*)(smA + ra * 128 + bya);
          }
      }
      __builtin_amdgcn_s_setprio(1);
#pragma unroll
      for (int e = 0; e < 2; ++e)
#pragma unroll
        for (int fc = 0; fc < 4; ++fc)
#pragma unroll
          for (int ks = 0; ks < 2; ++ks)
            acc[2 * p + e][fc] = __builtin_amdgcn_mfma_f32_16x16x32_bf16(
                afr[p & 1][e][ks], bfr[fc][ks], acc[2 * p + e][fc], 0, 0, 0);
      __builtin_amdgcn_s_setprio(0);
    }
  }
#undef STAGE_Q

  // epilogue
#pragma unroll
  for (int fr = 0; fr < 8; ++fr) {
#pragma unroll
    for (int j4 = 0; j4 < 4; ++j4) {
      int m = m0 + wr * 128 + fr * 16 + ((lane >> 4) << 2) + j4;
      if (m >= M) continue;
#pragma unroll
      for (int fc = 0; fc < 4; ++fc) {
        int n = n0 + wc * 64 + fc * 16 + (lane & 15);
        if (n >= N) continue;
        float v = acc[fr][fc][j4] * scale;
        if (bias) v += bias[n];
        if (EPI == 1) v = sigmoidf_(v);
        if (EPI == 2) {
          float g = sigmoidf_(v);
          float h  = (float)Gh[(size_t)m * 1024 + n];
          float hm = (float)Gm[(size_t)m * 1024 + n];
          v = g * h + (1.0f - g) * hm;
        }
        C[(size_t)m * ldc + c_off + n] = (TC)v;
        if (EPI == 2 && Cbf) Cbf[(size_t)m * 2048 + c_off + n] = (bf16)v;
      }
    }
  }
}

// ---------------- 128x128 MFMA GEMM (R17-proven; proj / V^T / QK^T / PV) ----------------
template <int EPI, typename TC>
__global__ __launch_bounds__(256, 2) void mgemm(
    const bf16* __restrict__ A, const bf16* __restrict__ A2, int ksplit,
    const bf16* __restrict__ Bt, const float* __restrict__ bias, TC* __restrict__ C,
    int M, int N, int K, int lda, int ldb, int ldc, int c_off, float scale,
    long long sA, long long sB, long long sC) {
  __shared__ __align__(16) char sm[16384];
  const int t = threadIdx.x;
  const long long bz = blockIdx.z;
  A += bz * sA; A2 += bz * sA; Bt += bz * sB; C += bz * sC;

  const int gx = gridDim.x;
  const int nwg = gx * gridDim.y;
  const int orig = blockIdx.y * gx + blockIdx.x;
  const int qq = nwg >> 3, r8 = nwg & 7;
  const int xcd = orig & 7, lo = orig >> 3;
  const int wg = (xcd < r8 ? xcd * (qq + 1) : r8 * (qq + 1) + (xcd - r8) * qq) + lo;
  const int m0 = (wg / gx) * 128, n0 = (wg % gx) * 128;

  f32x4 acc[4][4];
#pragma unroll
  for (int i = 0; i < 4; ++i)
#pragma unroll
    for (int j = 0; j < 4; ++j)
#pragma unroll
      for (int c = 0; c < 4; ++c) acc[i][j][c] = 0.0f;

  const int lane = t & 63;
  const int wv = t >> 6, wm = (wv >> 1) * 64, wn = (wv & 1) * 64;
  const int lr = lane & 15, lkb = (lane >> 4) * 16;
  const int rr = t >> 2, cc = (t & 3) * 8;

  for (int k0 = 0; k0 < K; k0 += 32) {
    const bf16* Ak = (k0 < ksplit) ? (A + k0) : (A2 + (k0 - ksplit));
    const bf16* Bk = Bt + k0;
#pragma unroll
    for (int j = 0; j < 2; ++j) {
      int ra = m0 + j * 64 + rr; ra = ra < M ? ra : M - 1;
      GLD_LDS16(Ak + (size_t)ra * lda + cc, sm + j * 4096 + t * 16);
      int rb = n0 + j * 64 + rr; rb = rb < N ? rb : N - 1;
      GLD_LDS16(Bk + (size_t)rb * ldb + cc, sm + 8192 + j * 4096 + t * 16);
    }
    asm volatile("s_waitcnt vmcnt(0)" ::: "memory");
    __syncthreads();

    bf16x8 av[4], bv[4];
#pragma unroll
    for (int i = 0; i < 4; ++i) {
      av[i] = *(const bf16x8*)(sm + (wm + i * 16 + lr) * 64 + lkb);
      bv[i] = *(const bf16x8*)(sm + 8192 + (wn + i * 16 + lr) * 64 + lkb);
    }
#pragma unroll
    for (int i = 0; i < 4; ++i)
#pragma unroll
      for (int j = 0; j < 4; ++j)
        acc[i][j] = __builtin_amdgcn_mfma_f32_16x16x32_bf16(av[i], bv[j], acc[i][j], 0, 0, 0);
    __syncthreads();
  }

#pragma unroll
  for (int i = 0; i < 4; ++i) {
#pragma unroll
    for (int j4 = 0; j4 < 4; ++j4) {
      int m = m0 + wm + i * 16 + (lane >> 4) * 4 + j4;
      if (m >= M) continue;
#pragma unroll
      for (int j = 0; j < 4; ++j) {
        int n = n0 + wn + j * 16 + (lane & 15);
        if (n >= N) continue;
        float v = acc[i][j][j4] * scale;
        if (bias) v += bias[n];
        if (EPI == 3) {
          unsigned b = (unsigned)m / 500u;
          unsigned s = (unsigned)m - b * 500u;
          C[(size_t)b * 524288 + (size_t)n * 512 + s] = (TC)v;
        } else {
          C[(size_t)m * ldc + c_off + n] = (TC)v;
        }
      }
    }
  }
}

// ---------------- masked softmax, wave-parallel ----------------
__global__ void attn_softmax_w(const float* __restrict__ S, bf16* __restrict__ P, int fw) {
  int row = blockIdx.x * 4 + (threadIdx.x >> 6);
  int lane = threadIdx.x & 63;
  int q = row % 500;
  const float* Srow = S + (size_t)row * 512;
  bf16* Prow = P + (size_t)row * 512;
  int klo = fw ? 0 : q;
  int khi = fw ? q : 499;

  float xv[8];
  float m = -1e30f;
#pragma unroll
  for (int i = 0; i < 8; ++i) {
    int k = lane + i * 64;
    bool valid = (k >= klo) & (k <= khi);
    float v = valid ? Srow[k] : -1e30f;
    xv[i] = v;
    m = fmaxf(m, v);
  }
#pragma unroll
  for (int off = 32; off > 0; off >>= 1) m = fmaxf(m, __shfl_xor(m, off, 64));
  float e[8];
  float sum = 0.0f;
#pragma unroll
  for (int i = 0; i < 8; ++i) {
    e[i] = (xv[i] > -1e29f) ? expf(xv[i] - m) : 0.0f;
    sum += e[i];
  }
#pragma unroll
  for (int off = 32; off > 0; off >>= 1) sum += __shfl_xor(sum, off, 64);
  float inv = 1.0f / sum;
#pragma unroll
  for (int i = 0; i < 8; ++i) Prow[lane + i * 64] = (bf16)(e[i] * inv);
}

// ---------------- final: online softmax over seq + weighted sum ----------------
__global__ void final_reduce_chunk(const float* __restrict__ s2, const float* __restrict__ Ci,
                                   float* __restrict__ utt) {
  int c = blockIdx.x * 256 + threadIdx.x;
  int b = blockIdx.y;
  if (c >= 2048) return;
  float m = -1e30f, sum = 0.0f, acc = 0.0f;
  for (int s = 0; s < 500; ++s) {
    size_t idx = ((size_t)(b * 500 + s)) * 2048 + c;
    float xx = s2[idx];
    float ci = Ci[idx];
    float mn = fmaxf(m, xx);
    float corr = expf(m - mn);
    float e = expf(xx - mn);
    sum = sum * corr + e;
    acc = acc * corr + e * ci;
    m = mn;
  }
  utt[(size_t)b * 2048 + c] = acc / sum;
}

// ---------------- launcher ----------------
extern "C" void kernel_launch(void* const* d_in, const int* in_sizes, int n_in,
                              void* d_out, int out_size, void* d_ws, size_t ws_size,
                              hipStream_t stream) {
  (void)in_sizes; (void)n_in; (void)out_size;
  float* utt = (float*)d_out;
  float* Ci  = (float*)d_out + 131072;

  const float* x     = (const float*)d_in[0];
  const float* pos   = (const float*)d_in[1];
  const float* Wq_fw = (const float*)d_in[2];  const float* bq_fw = (const float*)d_in[3];
  const float* Wk_fw = (const float*)d_in[4];  const float* bk_fw = (const float*)d_in[5];
  const float* Wv_fw = (const float*)d_in[6];  const float* bv_fw = (const float*)d_in[7];
  const float* Wq_bw = (const float*)d_in[8];  const float* bq_bw = (const float*)d_in[9];
  const float* Wk_bw = (const float*)d_in[10]; const float* bk_bw = (const float*)d_in[11];
  const float* Wv_bw = (const float*)d_in[12]; const float* bv_bw = (const float*)d_in[13];
  const float* Wg_fw = (const float*)d_in[14]; const float* bg_fw = (const float*)d_in[15];
  const float* Wg_bw = (const float*)d_in[16]; const float* bg_bw = (const float*)d_in[17];
  const float* W2    = (const float*)d_in[18]; const float* b2    = (const float*)d_in[19];
  const float* W1    = (const float*)d_in[20]; const float* b1    = (const float*)d_in[21];

  const size_t WS_BYTES = 465305600ull;
  if (ws_size < WS_BYTES) { fill_guard<<<512, 256, 0, stream>>>(utt, 500.0f); return; }

  char* wsb = (char*)d_ws;
  bf16*  Hbf  = (bf16*)(wsb);
  bf16*  Qb   = (bf16*)(wsb + 65536000);
  bf16*  Kb   = (bf16*)(wsb + 131072000);
  bf16*  Vt   = (bf16*)(wsb + 196608000);
  float* Sb   = (float*)(wsb + 263716864);
  bf16*  Hmb  = (bf16*)(wsb + 263716864);
  bf16*  Pb   = (bf16*)(wsb + 329252864);
  char*  wts  = wsb + 362020864;
  bf16* WqF = (bf16*)(wts);             bf16* WkF = (bf16*)(wts + 2097152);
  bf16* WvF = (bf16*)(wts + 4194304);   bf16* WqB = (bf16*)(wts + 6291456);
  bf16* WkB = (bf16*)(wts + 8388608);   bf16* WvB = (bf16*)(wts + 10485760);
  bf16* WgF = (bf16*)(wts + 12582912);  bf16* WgB = (bf16*)(wts + 16777216);
  bf16* W2t = (bf16*)(wts + 20971520);  bf16* W1t = (bf16*)(wts + 29360128);
  bf16*  Cibf  = (bf16*)(wsb + 399769600);
  bf16*  activ = (bf16*)(wsb + 131072000);
  float* s2b   = (float*)(wsb);

  hipFuncSetAttribute(reinterpret_cast<const void*>(&mgemm256<2, float>),
                      hipFuncAttributeMaxDynamicSharedMemorySize, 131072);
  hipFuncSetAttribute(reinterpret_cast<const void*>(&mgemm256<1, bf16>),
                      hipFuncAttributeMaxDynamicSharedMemorySize, 131072);
  hipFuncSetAttribute(reinterpret_cast<const void*>(&mgemm256<0, float>),
                      hipFuncAttributeMaxDynamicSharedMemorySize, 131072);

  add_pos_bf<<<32000, 256, 0, stream>>>(x, pos, Hbf);

  struct WT { const float* s; bf16* d; int R, C; } wt[10] = {
      {Wq_fw, WqF, 1024, 1024}, {Wk_fw, WkF, 1024, 1024}, {Wv_fw, WvF, 1024, 1024},
      {Wq_bw, WqB, 1024, 1024}, {Wk_bw, WkB, 1024, 1024}, {Wv_bw, WvB, 1024, 1024},
      {Wg_fw, WgF, 2048, 1024}, {Wg_bw, WgB, 2048, 1024},
      {W2,    W2t, 2048, 2048}, {W1,    W1t, 2048, 2048}};
  for (int i = 0; i < 10; ++i)
    wtrans<<<dim3(wt[i].C / 32, wt[i].R / 32), 256, 0, stream>>>(wt[i].s, wt[i].d, wt[i].R, wt[i].C);

  const int BIG = 1 << 30;
  for (int dir = 0; dir < 2; ++dir) {
    const bf16* WqT = dir ? WqB : WqF;  const float* bq = dir ? bq_bw : bq_fw;
    const bf16* WkT = dir ? WkB : WkF;  const float* bk = dir ? bk_bw : bk_fw;
    const bf16* WvT = dir ? WvB : WvF;  const float* bv = dir ? bv_bw : bv_fw;
    const bf16* WgT = dir ? WgB : WgF;  const float* bg = dir ? bg_bw : bg_fw;

    // Q/K = H @ W + b  (128^2, R17-proven)
    mgemm<0, bf16><<<dim3(8, 250, 1), 256, 0, stream>>>(
        Hbf, Hbf, BIG, WqT, bq, Qb, 32000, 1024, 1024, 1024, 1024, 1024, 0, 1.0f, 0, 0, 0);
    mgemm<0, bf16><<<dim3(8, 250, 1), 256, 0, stream>>>(
        Hbf, Hbf, BIG, WkT, bk, Kb, 32000, 1024, 1024, 1024, 1024, 1024, 0, 1.0f, 0, 0, 0);
    // V -> Vt[b][d][s]
    mgemm<3, bf16><<<dim3(8, 250, 1), 256, 0, stream>>>(
        Hbf, Hbf, BIG, WvT, bv, Vt, 32000, 1024, 1024, 1024, 1024, 512, 0, 1.0f, 0, 0, 0);
    // S = Q K^T / 32
    mgemm<0, float><<<dim3(4, 4, 64), 256, 0, stream>>>(
        Qb, Qb, BIG, Kb, nullptr, Sb, 500, 500, 1024, 1024, 1024, 512, 0, 0.03125f,
        512000, 512000, 256000);
    attn_softmax_w<<<8000, 256, 0, stream>>>(Sb, Pb, dir == 0 ? 1 : 0);
    // Hm = P @ V
    mgemm<0, bf16><<<dim3(8, 4, 64), 256, 0, stream>>>(
        Pb, Pb, BIG, Vt, nullptr, Hmb, 500, 1024, 512, 512, 512, 1024, 0, 1.0f,
        256000, 524288, 512000);
    // gate -> f32 Ci + bf16 Cibf (256^2 pipelined)
    mgemm256<2, float><<<dim3(8, 125), 512, 131072, stream>>>(
        Hbf, Hmb, 1024, WgT, bg, Ci, Cibf, 32000, 1024, 2048, 1024, 2048, 2048,
        dir == 0 ? 0 : 1024, 1.0f, Hbf, Hmb);
  }

  // activ = sigmoid(Cibf @ W2 + b2)
  mgemm256<1, bf16><<<dim3(8, 125), 512, 131072, stream>>>(
      Cibf, Cibf, BIG, W2t, b2, activ, nullptr, 32000, 2048, 2048, 2048, 2048, 2048, 0, 1.0f,
      nullptr, nullptr);

  // scores2 + online final reduce in 2 chunks of 32 batches
  for (int c0 = 0; c0 < 2; ++c0) {
    mgemm256<0, float><<<dim3(8, 63), 512, 131072, stream>>>(
        activ + (size_t)c0 * 16000 * 2048, activ, BIG, W1t, b1, s2b, nullptr,
        16000, 2048, 2048, 2048, 2048, 2048, 0, 1.0f, nullptr, nullptr);
    final_reduce_chunk<<<dim3(8, 32), 256, 0, stream>>>(
        s2b, Ci + (size_t)c0 * 32 * 500 * 2048, utt + (size_t)c0 * 32 * 2048);
  }
}

// Round 20
// 2400.842 us; speedup vs baseline: 1.1894x; 1.1776x over previous
//
#include <hip/hip_runtime.h>

typedef __bf16 bf16;
typedef __bf16 bf16x4 __attribute__((ext_vector_type(4)));
typedef __bf16 bf16x8 __attribute__((ext_vector_type(8)));
typedef float  f32x4  __attribute__((ext_vector_type(4)));
typedef unsigned int u32;

#define GLD_LDS16(gsrc, ldst) \
  __builtin_amdgcn_global_load_lds((const __attribute__((address_space(1))) u32*)(gsrc), \
                                   (__attribute__((address_space(3))) u32*)(ldst), 16, 0, 0)

static __device__ __forceinline__ float sigmoidf_(float x) { return 1.0f / (1.0f + expf(-x)); }

__global__ void fill_guard(float* __restrict__ utt, float v) {
  int i = blockIdx.x * 256 + threadIdx.x;
  if (i < 131072) utt[i] = v;
}

// ---------------- H = bf16(x + pos_emb) ----------------
__global__ void add_pos_bf(const float* __restrict__ x, const float* __restrict__ pos,
                           bf16* __restrict__ H) {
  size_t i = ((size_t)blockIdx.x * 256 + threadIdx.x) * 4;
  if (i >= 32768000ull) return;
  int d = (int)(i & 1023);
  int s = (int)((i >> 10) % 500);
  float4 xv = *(const float4*)(x + i);
  float4 pv = *(const float4*)(pos + (size_t)s * 1024 + d);
  bf16x4 o;
  o[0] = (bf16)(xv.x + pv.x); o[1] = (bf16)(xv.y + pv.y);
  o[2] = (bf16)(xv.z + pv.z); o[3] = (bf16)(xv.w + pv.w);
  *(bf16x4*)(H + i) = o;
}

// ---------------- weight transpose+convert: fp32 [R][C] -> bf16 [C][R] ----------------
__global__ void wtrans(const float* __restrict__ src, bf16* __restrict__ dst, int R, int C) {
  __shared__ float tile[32][33];
  int c0 = blockIdx.x * 32, r0 = blockIdx.y * 32;
  int tr = threadIdx.x >> 5, tc = threadIdx.x & 31;
#pragma unroll
  for (int i = 0; i < 4; ++i)
    tile[tr + i * 8][tc] = src[(size_t)(r0 + tr + i * 8) * C + c0 + tc];
  __syncthreads();
#pragma unroll
  for (int i = 0; i < 4; ++i) {
    int rr = tr + i * 8;
    dst[(size_t)(c0 + rr) * R + r0 + tc] = (bf16)tile[tc][rr];
  }
}

// ============ 128x128 MFMA GEMM, BK=64, both-sides XOR swizzle, XCD remap ============
// C[m,n] = scale*sum_k A[m,k]*Bt[n,k] (+bias[n]) + epilogue.
// EPI 0: plain. 1: sigmoid. 2: gate mix v=g*Gh+(1-g)*Gm, dual-write C(f32)+Cbf(bf16).
// EPI 4: fused proj: n<1024 -> C (Q); n<2048 -> Cbf (K, n-1024); else Cv scatter
//        Vt[b*524288 + (n-2048)*512 + s] (m = b*500+s). Per-segment bias: bias/biasK/biasV.
template <int EPI, typename TC>
__global__ __launch_bounds__(256, 2) void mgemm(
    const bf16* __restrict__ A, const bf16* __restrict__ A2, int ksplit,
    const bf16* __restrict__ Bt, const float* __restrict__ bias,
    const float* __restrict__ biasK, const float* __restrict__ biasV,
    TC* __restrict__ C, bf16* __restrict__ Cbf, bf16* __restrict__ Cv,
    int M, int N, int K, int lda, int ldb, int ldc, int c_off, float scale,
    long long sA, long long sB, long long sC,
    const bf16* __restrict__ Gh, const bf16* __restrict__ Gm) {
  __shared__ __align__(16) char sm[32768];  // A [128][64] @0, B @16384
  const int t = threadIdx.x;
  const long long bz = blockIdx.z;
  A += bz * sA; A2 += bz * sA; Bt += bz * sB; C += bz * sC;

  // T1: bijective XCD-aware block remap (m204)
  const int gx = gridDim.x;
  const int nwg = gx * gridDim.y;
  const int orig = blockIdx.y * gx + blockIdx.x;
  const int qq = nwg >> 3, r8 = nwg & 7;
  const int xcd = orig & 7, lo = orig >> 3;
  const int wg = (xcd < r8 ? xcd * (qq + 1) : r8 * (qq + 1) + (xcd - r8) * qq) + lo;
  const int m0 = (wg / gx) * 128, n0 = (wg % gx) * 128;

  f32x4 acc[4][4];
#pragma unroll
  for (int i = 0; i < 4; ++i)
#pragma unroll
    for (int j = 0; j < 4; ++j)
#pragma unroll
      for (int c = 0; c < 4; ++c) acc[i][j][c] = 0.0f;

  const int lane = t & 63;
  const int wv = t >> 6, wm = (wv >> 1) * 64, wn = (wv & 1) * 64;
  const int lr = lane & 15, lhi = lane >> 4;
  const int srow8 = t >> 3, sch = t & 7;  // staging: 32-row groups, 8 chunks/row

  for (int k0 = 0; k0 < K; k0 += 64) {
    const bf16* Ak = (k0 < ksplit) ? (A + k0) : (A2 + (k0 - ksplit));
    const bf16* Bk = Bt + k0;
#pragma unroll
    for (int i = 0; i < 4; ++i) {
      int rl = i * 32 + srow8;
      int ra = m0 + rl; ra = ra < M ? ra : M - 1;
      int ca = (sch ^ (ra & 7)) * 8;                   // pre-swizzled global chunk
      GLD_LDS16(Ak + (size_t)ra * lda + ca, sm + rl * 128 + sch * 16);
      int rb = n0 + rl; rb = rb < N ? rb : N - 1;
      int cb = (sch ^ (rb & 7)) * 8;
      GLD_LDS16(Bk + (size_t)rb * ldb + cb, sm + 16384 + rl * 128 + sch * 16);
    }
    asm volatile("s_waitcnt vmcnt(0)" ::: "memory");
    __syncthreads();

    bf16x8 av[4][2], bv[4][2];
#pragma unroll
    for (int i = 0; i < 4; ++i)
#pragma unroll
      for (int ks = 0; ks < 2; ++ks) {
        int ra = wm + i * 16 + lr;
        int ga = ks * 4 + lhi;
        av[i][ks] = *(const bf16x8*)(sm + ra * 128 + ((ga ^ (ra & 7)) << 4));
        int rb = wn + i * 16 + lr;
        bv[i][ks] = *(const bf16x8*)(sm + 16384 + rb * 128 + ((ga ^ (rb & 7)) << 4));
      }
#pragma unroll
    for (int ks = 0; ks < 2; ++ks)
#pragma unroll
      for (int i = 0; i < 4; ++i)
#pragma unroll
        for (int j = 0; j < 4; ++j)
          acc[i][j] = __builtin_amdgcn_mfma_f32_16x16x32_bf16(av[i][ks], bv[j][ks],
                                                              acc[i][j], 0, 0, 0);
    __syncthreads();
  }

  // D elem j4 of frag (i,j): row = wm+i*16+(lane>>4)*4+j4, col = wn+j*16+(lane&15)
#pragma unroll
  for (int i = 0; i < 4; ++i) {
#pragma unroll
    for (int j4 = 0; j4 < 4; ++j4) {
      int m = m0 + wm + i * 16 + lhi * 4 + j4;
      if (m >= M) continue;
#pragma unroll
      for (int j = 0; j < 4; ++j) {
        int n = n0 + wn + j * 16 + lr;
        if (n >= N) continue;
        float v = acc[i][j][j4] * scale;
        if (EPI == 4) {
          const float* bp = (n < 1024) ? bias : (n < 2048) ? biasK : biasV;
          v += bp[n & 1023];
          unsigned b = (unsigned)m / 500u;
          unsigned s = (unsigned)m - b * 500u;
          if (n < 1024)       C  [(size_t)m * 1024 + n] = (TC)v;
          else if (n < 2048)  Cbf[(size_t)m * 1024 + (n - 1024)] = (bf16)v;
          else                Cv [(size_t)b * 524288 + (size_t)(n - 2048) * 512 + s] = (bf16)v;
          continue;
        }
        if (bias) v += bias[n];
        if (EPI == 1) v = sigmoidf_(v);
        if (EPI == 2) {
          float g = sigmoidf_(v);
          float h  = (float)Gh[(size_t)m * 1024 + n];
          float hm = (float)Gm[(size_t)m * 1024 + n];
          v = g * h + (1.0f - g) * hm;
        }
        C[(size_t)m * ldc + c_off + n] = (TC)v;
        if (EPI == 2 && Cbf) Cbf[(size_t)m * 2048 + c_off + n] = (bf16)v;
      }
    }
  }
}

// ---------------- masked softmax, wave-parallel ----------------
__global__ void attn_softmax_w(const float* __restrict__ S, bf16* __restrict__ P, int fw) {
  int row = blockIdx.x * 4 + (threadIdx.x >> 6);
  int lane = threadIdx.x & 63;
  int q = row % 500;
  const float* Srow = S + (size_t)row * 512;
  bf16* Prow = P + (size_t)row * 512;
  int klo = fw ? 0 : q;
  int khi = fw ? q : 499;

  float xv[8];
  float m = -1e30f;
#pragma unroll
  for (int i = 0; i < 8; ++i) {
    int k = lane + i * 64;
    bool valid = (k >= klo) & (k <= khi);
    float v = valid ? Srow[k] : -1e30f;
    xv[i] = v;
    m = fmaxf(m, v);
  }
#pragma unroll
  for (int off = 32; off > 0; off >>= 1) m = fmaxf(m, __shfl_xor(m, off, 64));
  float e[8];
  float sum = 0.0f;
#pragma unroll
  for (int i = 0; i < 8; ++i) {
    e[i] = (xv[i] > -1e29f) ? expf(xv[i] - m) : 0.0f;
    sum += e[i];
  }
#pragma unroll
  for (int off = 32; off > 0; off >>= 1) sum += __shfl_xor(sum, off, 64);
  float inv = 1.0f / sum;
#pragma unroll
  for (int i = 0; i < 8; ++i) Prow[lane + i * 64] = (bf16)(e[i] * inv);
}

// ---------------- final: online softmax over seq + weighted sum ----------------
__global__ void final_reduce_chunk(const float* __restrict__ s2, const float* __restrict__ Ci,
                                   float* __restrict__ utt) {
  int c = blockIdx.x * 256 + threadIdx.x;
  int b = blockIdx.y;
  if (c >= 2048) return;
  float m = -1e30f, sum = 0.0f, acc = 0.0f;
  for (int s = 0; s < 500; ++s) {
    size_t idx = ((size_t)(b * 500 + s)) * 2048 + c;
    float xx = s2[idx];
    float ci = Ci[idx];
    float mn = fmaxf(m, xx);
    float corr = expf(m - mn);
    float e = expf(xx - mn);
    sum = sum * corr + e;
    acc = acc * corr + e * ci;
    m = mn;
  }
  utt[(size_t)b * 2048 + c] = acc / sum;
}

// ---------------- launcher ----------------
extern "C" void kernel_launch(void* const* d_in, const int* in_sizes, int n_in,
                              void* d_out, int out_size, void* d_ws, size_t ws_size,
                              hipStream_t stream) {
  (void)in_sizes; (void)n_in; (void)out_size;
  float* utt = (float*)d_out;
  float* Ci  = (float*)d_out + 131072;

  const float* x     = (const float*)d_in[0];
  const float* pos   = (const float*)d_in[1];
  const float* Wq_fw = (const float*)d_in[2];  const float* bq_fw = (const float*)d_in[3];
  const float* Wk_fw = (const float*)d_in[4];  const float* bk_fw = (const float*)d_in[5];
  const float* Wv_fw = (const float*)d_in[6];  const float* bv_fw = (const float*)d_in[7];
  const float* Wq_bw = (const float*)d_in[8];  const float* bq_bw = (const float*)d_in[9];
  const float* Wk_bw = (const float*)d_in[10]; const float* bk_bw = (const float*)d_in[11];
  const float* Wv_bw = (const float*)d_in[12]; const float* bv_bw = (const float*)d_in[13];
  const float* Wg_fw = (const float*)d_in[14]; const float* bg_fw = (const float*)d_in[15];
  const float* Wg_bw = (const float*)d_in[16]; const float* bg_bw = (const float*)d_in[17];
  const float* W2    = (const float*)d_in[18]; const float* b2    = (const float*)d_in[19];
  const float* W1    = (const float*)d_in[20]; const float* b1    = (const float*)d_in[21];

  // ws layout identical to R17 (guard-proven 465,305,600):
  const size_t WS_BYTES = 465305600ull;
  if (ws_size < WS_BYTES) { fill_guard<<<512, 256, 0, stream>>>(utt, 500.0f); return; }

  char* wsb = (char*)d_ws;
  bf16*  Hbf  = (bf16*)(wsb);
  bf16*  Qb   = (bf16*)(wsb + 65536000);
  bf16*  Kb   = (bf16*)(wsb + 131072000);
  bf16*  Vt   = (bf16*)(wsb + 196608000);
  float* Sb   = (float*)(wsb + 263716864);
  bf16*  Hmb  = (bf16*)(wsb + 263716864);   // alias S after softmax
  bf16*  Pb   = (bf16*)(wsb + 329252864);
  char*  wts  = wsb + 362020864;
  bf16* WqF = (bf16*)(wts);             // WqF/WkF/WvF contiguous -> fused proj B (N=3072)
  bf16* WqB = (bf16*)(wts + 6291456);   // WqB/WkB/WvB contiguous
  bf16* WgF = (bf16*)(wts + 12582912);  bf16* WgB = (bf16*)(wts + 16777216);
  bf16* W2t = (bf16*)(wts + 20971520);  bf16* W1t = (bf16*)(wts + 29360128);
  bf16*  Cibf  = (bf16*)(wsb + 399769600);
  bf16*  activ = (bf16*)(wsb + 131072000);  // alias K+Vt head (post-attention)
  float* s2b   = (float*)(wsb);             // alias Hbf+Q (post-gates)

  add_pos_bf<<<32000, 256, 0, stream>>>(x, pos, Hbf);

  struct WT { const float* s; bf16* d; int R, C; } wt[10] = {
      {Wq_fw, WqF, 1024, 1024}, {Wk_fw, (bf16*)(wts + 2097152), 1024, 1024},
      {Wv_fw, (bf16*)(wts + 4194304), 1024, 1024}, {Wq_bw, WqB, 1024, 1024},
      {Wk_bw, (bf16*)(wts + 8388608), 1024, 1024}, {Wv_bw, (bf16*)(wts + 10485760), 1024, 1024},
      {Wg_fw, WgF, 2048, 1024}, {Wg_bw, WgB, 2048, 1024},
      {W2,    W2t, 2048, 2048}, {W1,    W1t, 2048, 2048}};
  for (int i = 0; i < 10; ++i)
    wtrans<<<dim3(wt[i].C / 32, wt[i].R / 32), 256, 0, stream>>>(wt[i].s, wt[i].d, wt[i].R, wt[i].C);

  const int BIG = 1 << 30;
  for (int dir = 0; dir < 2; ++dir) {
    const bf16* WqkvT = dir ? WqB : WqF;   // contiguous [3072][1024]
    const bf16* WgT = dir ? WgB : WgF;
    const float* bq = dir ? bq_bw : bq_fw;
    const float* bk = dir ? bk_bw : bk_fw;
    const float* bv = dir ? bv_bw : bv_fw;
    const float* bg = dir ? bg_bw : bg_fw;

    // fused Q/K/Vt projection: [32000,1024] x [3072,1024]^T
    mgemm<4, bf16><<<dim3(24, 250, 1), 256, 0, stream>>>(
        Hbf, Hbf, BIG, WqkvT, bq, bk, bv, Qb, Kb, Vt,
        32000, 3072, 1024, 1024, 1024, 1024, 0, 1.0f, 0, 0, 0, nullptr, nullptr);
    // S = Q K^T / 32   f32 [64][500][512]
    mgemm<0, float><<<dim3(4, 4, 64), 256, 0, stream>>>(
        Qb, Qb, BIG, Kb, nullptr, nullptr, nullptr, Sb, nullptr, nullptr,
        500, 500, 1024, 1024, 1024, 512, 0, 0.03125f, 512000, 512000, 256000,
        nullptr, nullptr);
    attn_softmax_w<<<8000, 256, 0, stream>>>(Sb, Pb, dir == 0 ? 1 : 0);
    // Hm = P @ V   (K=512)
    mgemm<0, bf16><<<dim3(8, 4, 64), 256, 0, stream>>>(
        Pb, Pb, BIG, Vt, nullptr, nullptr, nullptr, Hmb, nullptr, nullptr,
        500, 1024, 512, 512, 512, 1024, 0, 1.0f, 256000, 524288, 512000,
        nullptr, nullptr);
    // gate -> f32 Ci + bf16 Cibf (split A at 1024)
    mgemm<2, float><<<dim3(8, 250, 1), 256, 0, stream>>>(
        Hbf, Hmb, 1024, WgT, bg, nullptr, nullptr, Ci, Cibf, nullptr,
        32000, 1024, 2048, 1024, 2048, 2048, dir == 0 ? 0 : 1024, 1.0f, 0, 0, 0,
        Hbf, Hmb);
  }

  // activ = sigmoid(Cibf @ W2 + b2)
  mgemm<1, bf16><<<dim3(16, 250, 1), 256, 0, stream>>>(
      Cibf, Cibf, BIG, W2t, b2, nullptr, nullptr, activ, nullptr, nullptr,
      32000, 2048, 2048, 2048, 2048, 2048, 0, 1.0f, 0, 0, 0, nullptr, nullptr);

  // scores2 + online final reduce in 2 chunks of 32 batches
  for (int c0 = 0; c0 < 2; ++c0) {
    mgemm<0, float><<<dim3(16, 125, 1), 256, 0, stream>>>(
        activ + (size_t)c0 * 16000 * 2048, activ, BIG, W1t, b1, nullptr, nullptr,
        s2b, nullptr, nullptr, 16000, 2048, 2048, 2048, 2048, 2048, 0, 1.0f,
        0, 0, 0, nullptr, nullptr);
    final_reduce_chunk<<<dim3(8, 32), 256, 0, stream>>>(
        s2b, Ci + (size_t)c0 * 32 * 500 * 2048, utt + (size_t)c0 * 32 * 2048);
  }
}